// Round 2
// baseline (1332.715 us; speedup 1.0000x reference)
//
#include <hip/hip_runtime.h>

#define N_OBJ  20000
#define N_ROOM 500
#define N_ATTR 2000
#define IN_F   300
#define HDIM   512
#define E_OO   640000
#define E_RO   50000
#define E_AO   100000
#define BATCH  8

// ---------------------------------------------------------------------------
// Degree counting (all 3 relations in one grid)
// ---------------------------------------------------------------------------
__global__ void count_edges(const int* __restrict__ src_oo, const int* __restrict__ dst_oo,
                            const int* __restrict__ src_ro, const int* __restrict__ dst_ro,
                            const int* __restrict__ src_ao, const int* __restrict__ dst_ao,
                            int* cnt_src_oo, int* cnt_src_ro, int* cnt_src_ao,
                            int* cnt_dst_oo, int* cnt_dst_ro, int* cnt_dst_ao)
{
    int e = blockIdx.x * blockDim.x + threadIdx.x;
    const int total = E_OO + E_RO + E_AO;
    if (e >= total) return;
    if (e < E_OO) {
        atomicAdd(&cnt_src_oo[src_oo[e]], 1);
        atomicAdd(&cnt_dst_oo[dst_oo[e]], 1);
    } else if (e < E_OO + E_RO) {
        int i = e - E_OO;
        atomicAdd(&cnt_src_ro[src_ro[i]], 1);
        atomicAdd(&cnt_dst_ro[dst_ro[i]], 1);
    } else {
        int i = e - E_OO - E_RO;
        atomicAdd(&cnt_src_ao[src_ao[i]], 1);
        atomicAdd(&cnt_dst_ao[dst_ao[i]], 1);
    }
}

// ---------------------------------------------------------------------------
// Exclusive prefix-sum of the 3 dst-degree arrays (each n = N_OBJ).
// One block per relation, 1024 threads, 20 elements per thread.
// Writes row_ptr[0..n] and cursor[0..n-1] (= row_ptr copy for the fill pass).
// ---------------------------------------------------------------------------
__global__ __launch_bounds__(1024)
void scan3(const int* c0, const int* c1, const int* c2,
           int* r0, int* r1, int* r2,
           int* u0, int* u1, int* u2)
{
    const int n = N_OBJ;
    const int* cnt = (blockIdx.x == 0) ? c0 : (blockIdx.x == 1 ? c1 : c2);
    int* rp  = (blockIdx.x == 0) ? r0 : (blockIdx.x == 1 ? r1 : r2);
    int* cur = (blockIdx.x == 0) ? u0 : (blockIdx.x == 1 ? u1 : u2);

    __shared__ int part[1024];
    int t  = threadIdx.x;
    int lo = t * 20;
    int hi = lo + 20 < n ? lo + 20 : n;

    int local = 0;
    for (int i = lo; i < hi; ++i) local += cnt[i];
    part[t] = local;
    __syncthreads();
    for (int off = 1; off < 1024; off <<= 1) {
        int v = (t >= off) ? part[t - off] : 0;
        __syncthreads();
        part[t] += v;
        __syncthreads();
    }
    int run = part[t] - local;   // exclusive prefix for this thread's chunk
    for (int i = lo; i < hi; ++i) {
        rp[i]  = run;
        cur[i] = run;
        run += cnt[i];
    }
    if (t == 1023) rp[n] = part[1023];
}

// ---------------------------------------------------------------------------
// norm = 1/sqrt(max(deg,1)) for the 6 degree arrays
// ---------------------------------------------------------------------------
__global__ void norms6(const int* c0, const int* c1, const int* c2,
                       const int* c3, const int* c4, const int* c5,
                       float* n0, float* n1, float* n2,
                       float* n3, float* n4, float* n5,
                       int s0, int s1, int s2, int s3, int s4, int s5)
{
    const int* c; float* o; int n;
    switch (blockIdx.y) {
        case 0:  c = c0; o = n0; n = s0; break;
        case 1:  c = c1; o = n1; n = s1; break;
        case 2:  c = c2; o = n2; n = s2; break;
        case 3:  c = c3; o = n3; n = s3; break;
        case 4:  c = c4; o = n4; n = s4; break;
        default: c = c5; o = n5; n = s5; break;
    }
    int i = blockIdx.x * blockDim.x + threadIdx.x;
    if (i < n) {
        int d = c[i];
        if (d < 1) d = 1;
        o[i] = 1.0f / sqrtf((float)d);
    }
}

// ---------------------------------------------------------------------------
// Fill CSR column (src id) arrays using atomic cursors
// ---------------------------------------------------------------------------
__global__ void fill_edges(const int* __restrict__ src_oo, const int* __restrict__ dst_oo,
                           const int* __restrict__ src_ro, const int* __restrict__ dst_ro,
                           const int* __restrict__ src_ao, const int* __restrict__ dst_ao,
                           int* cur_oo, int* cur_ro, int* cur_ao,
                           int* col_oo, int* col_ro, int* col_ao)
{
    int e = blockIdx.x * blockDim.x + threadIdx.x;
    const int total = E_OO + E_RO + E_AO;
    if (e >= total) return;
    if (e < E_OO) {
        int pos = atomicAdd(&cur_oo[dst_oo[e]], 1);
        col_oo[pos] = src_oo[e];
    } else if (e < E_OO + E_RO) {
        int i = e - E_OO;
        int pos = atomicAdd(&cur_ro[dst_ro[i]], 1);
        col_ro[pos] = src_ro[i];
    } else {
        int i = e - E_OO - E_RO;
        int pos = atomicAdd(&cur_ao[dst_ao[i]], 1);
        col_ao[pos] = src_ao[i];
    }
}

// ---------------------------------------------------------------------------
// CSR row aggregation: out[d][f] = ndst[d] * sum_{s in row d} feat[s][f]*nsrc[s]*scale
// One block (256 threads) per dst row; threads split the feature dim.
// F is 300 or 512, so each thread handles f and f+256.
// ---------------------------------------------------------------------------
__global__ __launch_bounds__(256)
void agg_csr(const float* __restrict__ feat, int F,
             const int* __restrict__ rp, const int* __restrict__ col,
             const float* __restrict__ nsrc, const float* __restrict__ ndst,
             float scale, float* __restrict__ out)
{
    int d = blockIdx.x;
    int t = threadIdx.x;
    int a = rp[d], b = rp[d + 1];
    int f1 = t + 256;
    bool has1 = (f1 < F);
    float acc0 = 0.f, acc1 = 0.f;
    for (int j = a; j < b; ++j) {
        int s = col[j];
        float ns = nsrc[s] * scale;
        acc0 += feat[(long long)s * F + t] * ns;
        if (has1) acc1 += feat[(long long)s * F + f1] * ns;
    }
    float nd = ndst[d];
    out[(long long)d * F + t] = acc0 * nd;
    if (has1) out[(long long)d * F + f1] = acc1 * nd;
}

// ---------------------------------------------------------------------------
// fp32 GEMM: C[M x 512] (+)= [relu](A[M x K] @ W[K x 512] + bias)
// Tile 128x64, BK=16, 256 threads, 8x4 micro-tile per thread.
// A staged transposed in LDS (pad +4 keeps 16B alignment, <=2-way banks).
// ---------------------------------------------------------------------------
template<int RELU, int ACCUM>
__global__ __launch_bounds__(256)
void gemm512(const float* __restrict__ A, const float* __restrict__ W,
             const float* __restrict__ bias, float* __restrict__ C,
             int M, int K)
{
    const int BM = 128, BN = 64, BK = 16;
    __shared__ float As[BK][BM + 4];   // [k][m], row = 132 floats (16B-aligned)
    __shared__ float Bs[BK][BN];       // [k][n]

    int tid = threadIdx.x;
    int tx = tid & 15;     // n group (4 cols)
    int ty = tid >> 4;     // m group (8 rows)
    int m0 = blockIdx.x * BM;
    int n0 = blockIdx.y * BN;

    float acc[8][4];
#pragma unroll
    for (int i = 0; i < 8; ++i)
#pragma unroll
        for (int j = 0; j < 4; ++j) acc[i][j] = 0.f;

    int art = tid >> 2;          // 0..63  (A row within tile, +64 for 2nd)
    int act = (tid & 3) * 4;     // 0,4,8,12 (A col within k-tile)
    int brt = tid >> 4;          // 0..15  (B k-row)
    int bct = (tid & 15) * 4;    // B col

    for (int k0 = 0; k0 < K; k0 += BK) {
#pragma unroll
        for (int h = 0; h < 2; ++h) {
            int am = m0 + art + h * 64;
            int ak = k0 + act;
            float4 av = make_float4(0.f, 0.f, 0.f, 0.f);
            if (am < M && ak < K)
                av = *(const float4*)(A + (long long)am * K + ak);
            As[act + 0][art + h * 64] = av.x;
            As[act + 1][art + h * 64] = av.y;
            As[act + 2][art + h * 64] = av.z;
            As[act + 3][art + h * 64] = av.w;
        }
        {
            int bk = k0 + brt;
            float4 bv = make_float4(0.f, 0.f, 0.f, 0.f);
            if (bk < K)
                bv = *(const float4*)(W + (long long)bk * HDIM + n0 + bct);
            *(float4*)&Bs[brt][bct] = bv;
        }
        __syncthreads();
#pragma unroll
        for (int kk = 0; kk < BK; ++kk) {
            float4 a0 = *(const float4*)&As[kk][ty * 8];
            float4 a1 = *(const float4*)&As[kk][ty * 8 + 4];
            float4 b0 = *(const float4*)&Bs[kk][tx * 4];
            float a[8] = {a0.x, a0.y, a0.z, a0.w, a1.x, a1.y, a1.z, a1.w};
            float b[4] = {b0.x, b0.y, b0.z, b0.w};
#pragma unroll
            for (int i = 0; i < 8; ++i)
#pragma unroll
                for (int j = 0; j < 4; ++j)
                    acc[i][j] = fmaf(a[i], b[j], acc[i][j]);
        }
        __syncthreads();
    }

    float4 b4 = *(const float4*)(bias + n0 + tx * 4);
#pragma unroll
    for (int i = 0; i < 8; ++i) {
        int m = m0 + ty * 8 + i;
        if (m < M) {
            float4 v;
            v.x = acc[i][0] + b4.x;
            v.y = acc[i][1] + b4.y;
            v.z = acc[i][2] + b4.z;
            v.w = acc[i][3] + b4.w;
            if (RELU) {
                v.x = fmaxf(v.x, 0.f); v.y = fmaxf(v.y, 0.f);
                v.z = fmaxf(v.z, 0.f); v.w = fmaxf(v.w, 0.f);
            }
            long long o = (long long)m * HDIM + n0 + tx * 4;
            if (ACCUM) {
                float4 old = *(const float4*)(C + o);
                v.x += old.x; v.y += old.y; v.z += old.z; v.w += old.w;
            }
            *(float4*)(C + o) = v;
        }
    }
}

// ---------------------------------------------------------------------------
// Broadcast slice 0 of d_out into slices 1..7
// ---------------------------------------------------------------------------
__global__ void bcast8(const float4* __restrict__ src, float4* __restrict__ dst)
{
    const long long slice4 = (long long)N_OBJ * HDIM / 4;   // float4 units
    long long i = (long long)blockIdx.x * blockDim.x + threadIdx.x;
    float4 v = src[i];
#pragma unroll
    for (int c = 1; c < BATCH; ++c)
        dst[c * slice4 + i] = v;
}

// ---------------------------------------------------------------------------
extern "C" void kernel_launch(void* const* d_in, const int* in_sizes, int n_in,
                              void* d_out, int out_size, void* d_ws, size_t ws_size,
                              hipStream_t stream)
{
    const float* feat_object = (const float*)d_in[1];
    const float* feat_room   = (const float*)d_in[2];
    const float* feat_attr   = (const float*)d_in[3];
    const float* W1i = (const float*)d_in[4];
    const float* b1i = (const float*)d_in[5];
    const float* W1b = (const float*)d_in[6];
    const float* b1b = (const float*)d_in[7];
    const float* W2  = (const float*)d_in[8];
    const float* b2  = (const float*)d_in[9];
    const int* src_oo = (const int*)d_in[10];
    const int* dst_oo = (const int*)d_in[11];
    const int* src_ro = (const int*)d_in[12];
    const int* dst_ro = (const int*)d_in[13];
    const int* src_ao = (const int*)d_in[14];
    const int* dst_ao = (const int*)d_in[15];
    float* out = (float*)d_out;

    // ALL scratch lives inside d_out, which is 8 slices of [N_OBJ x HDIM] floats
    // (40.96 MB each), all dead until the final bcast8:
    //   slice 6: h_sum (conv1 accumulated output)
    //   slice 7: scr   (agg buffer, A-operand of each GEMM)
    //   slice 1: small CSR/norm scratch (~4.6 MB; no dependence on ws_size)
    const long long slice = (long long)N_OBJ * HDIM;   // 10,240,000 floats
    float* h_sum = out + 6 * slice;
    float* scr   = out + 7 * slice;

    char* w = (char*)(out + 1 * slice);
    size_t off = 0;
    auto alloc = [&](size_t bytes) -> void* {
        void* p = w + off;
        off += (bytes + 255) & ~(size_t)255;
        return p;
    };
    float* n_src_oo = (float*)alloc(N_OBJ  * 4);
    float* n_src_ro = (float*)alloc(N_ROOM * 4);
    float* n_src_ao = (float*)alloc(N_ATTR * 4);
    float* n_dst_oo = (float*)alloc(N_OBJ * 4);
    float* n_dst_ro = (float*)alloc(N_OBJ * 4);
    float* n_dst_ao = (float*)alloc(N_OBJ * 4);

    const int CNT_TOTAL = N_OBJ + 512 + 2048 + 3 * N_OBJ;   // 82,560 ints
    int* cnt_blk    = (int*)alloc((size_t)CNT_TOTAL * 4);
    int* cnt_src_oo = cnt_blk;
    int* cnt_src_ro = cnt_src_oo + N_OBJ;
    int* cnt_src_ao = cnt_src_ro + 512;
    int* cnt_dst_oo = cnt_src_ao + 2048;
    int* cnt_dst_ro = cnt_dst_oo + N_OBJ;
    int* cnt_dst_ao = cnt_dst_ro + N_OBJ;

    int* rp_oo  = (int*)alloc((N_OBJ + 1) * 4);
    int* rp_ro  = (int*)alloc((N_OBJ + 1) * 4);
    int* rp_ao  = (int*)alloc((N_OBJ + 1) * 4);
    int* cur_oo = (int*)alloc(N_OBJ * 4);
    int* cur_ro = (int*)alloc(N_OBJ * 4);
    int* cur_ao = (int*)alloc(N_OBJ * 4);
    int* col_oo = (int*)alloc((size_t)E_OO * 4);
    int* col_ro = (int*)alloc((size_t)E_RO * 4);
    int* col_ao = (int*)alloc((size_t)E_AO * 4);

    // ---- CSR build ----
    hipMemsetAsync(cnt_blk, 0, (size_t)CNT_TOTAL * 4, stream);

    const int TOTAL_E = E_OO + E_RO + E_AO;
    int egrid = (TOTAL_E + 255) / 256;
    count_edges<<<egrid, 256, 0, stream>>>(src_oo, dst_oo, src_ro, dst_ro, src_ao, dst_ao,
                                           cnt_src_oo, cnt_src_ro, cnt_src_ao,
                                           cnt_dst_oo, cnt_dst_ro, cnt_dst_ao);
    scan3<<<3, 1024, 0, stream>>>(cnt_dst_oo, cnt_dst_ro, cnt_dst_ao,
                                  rp_oo, rp_ro, rp_ao,
                                  cur_oo, cur_ro, cur_ao);
    norms6<<<dim3((N_OBJ + 255) / 256, 6), 256, 0, stream>>>(
        cnt_src_oo, cnt_src_ro, cnt_src_ao, cnt_dst_oo, cnt_dst_ro, cnt_dst_ao,
        n_src_oo, n_src_ro, n_src_ao, n_dst_oo, n_dst_ro, n_dst_ao,
        N_OBJ, N_ROOM, N_ATTR, N_OBJ, N_OBJ, N_OBJ);
    fill_edges<<<egrid, 256, 0, stream>>>(src_oo, dst_oo, src_ro, dst_ro, src_ao, dst_ao,
                                          cur_oo, cur_ro, cur_ao,
                                          col_oo, col_ro, col_ao);

    // ---- conv1: three relations, all dst=object, mean afterwards ----
    dim3 ggrid((N_OBJ + 127) / 128, HDIM / 64);

    agg_csr<<<N_OBJ, 256, 0, stream>>>(feat_object, IN_F, rp_oo, col_oo,
                                       n_src_oo, n_dst_oo, 1.0f, scr);
    gemm512<1, 0><<<ggrid, 256, 0, stream>>>(scr, W1i, b1i, h_sum, N_OBJ, IN_F);

    agg_csr<<<N_OBJ, 256, 0, stream>>>(feat_room, IN_F, rp_ro, col_ro,
                                       n_src_ro, n_dst_ro, 1.0f, scr);
    gemm512<1, 1><<<ggrid, 256, 0, stream>>>(scr, W1i, b1i, h_sum, N_OBJ, IN_F);

    agg_csr<<<N_OBJ, 256, 0, stream>>>(feat_attr, IN_F, rp_ao, col_ao,
                                       n_src_ao, n_dst_ao, 1.0f, scr);
    gemm512<1, 1><<<ggrid, 256, 0, stream>>>(scr, W1b, b1b, h_sum, N_OBJ, IN_F);

    // ---- conv2: object->object on h_obj = h_sum/3 (scale folded into agg) ----
    agg_csr<<<N_OBJ, 256, 0, stream>>>(h_sum, HDIM, rp_oo, col_oo,
                                       n_src_oo, n_dst_oo, 1.0f / 3.0f, scr);
    gemm512<0, 0><<<ggrid, 256, 0, stream>>>(scr, W2, b2, out, N_OBJ, HDIM);

    // ---- broadcast slice 0 -> slices 1..7 (overwrites all scratch, now dead) ----
    const long long slice4 = slice / 4;
    bcast8<<<(unsigned)(slice4 / 256), 256, 0, stream>>>((const float4*)out, (float4*)out);
}

// Round 3
// 1181.346 us; speedup vs baseline: 1.1281x; 1.1281x over previous
//
#include <hip/hip_runtime.h>

#define N_OBJ  20000
#define N_ROOM 500
#define N_ATTR 2000
#define IN_F   300
#define HDIM   512
#define E_OO   640000
#define E_RO   50000
#define E_AO   100000
#define BATCH  8

typedef __attribute__((ext_vector_type(8))) __bf16 bf16x8;
typedef __attribute__((ext_vector_type(4))) float  f32x4;

// ---- float -> bf16 (round-to-nearest-even), as raw bits ----
__device__ inline unsigned short f2bf_rn(float x)
{
    unsigned u = __float_as_uint(x);
    unsigned r = (u + 0x7fffu + ((u >> 16) & 1u)) >> 16;
    return (unsigned short)r;
}
__device__ inline float bf2f(unsigned short h)
{
    return __uint_as_float(((unsigned)h) << 16);
}

// ---------------------------------------------------------------------------
// Degree counting (all 3 relations in one grid)
// ---------------------------------------------------------------------------
__global__ void count_edges(const int* __restrict__ src_oo, const int* __restrict__ dst_oo,
                            const int* __restrict__ src_ro, const int* __restrict__ dst_ro,
                            const int* __restrict__ src_ao, const int* __restrict__ dst_ao,
                            int* cnt_src_oo, int* cnt_src_ro, int* cnt_src_ao,
                            int* cnt_dst_oo, int* cnt_dst_ro, int* cnt_dst_ao)
{
    int e = blockIdx.x * blockDim.x + threadIdx.x;
    const int total = E_OO + E_RO + E_AO;
    if (e >= total) return;
    if (e < E_OO) {
        atomicAdd(&cnt_src_oo[src_oo[e]], 1);
        atomicAdd(&cnt_dst_oo[dst_oo[e]], 1);
    } else if (e < E_OO + E_RO) {
        int i = e - E_OO;
        atomicAdd(&cnt_src_ro[src_ro[i]], 1);
        atomicAdd(&cnt_dst_ro[dst_ro[i]], 1);
    } else {
        int i = e - E_OO - E_RO;
        atomicAdd(&cnt_src_ao[src_ao[i]], 1);
        atomicAdd(&cnt_dst_ao[dst_ao[i]], 1);
    }
}

// ---------------------------------------------------------------------------
// Exclusive prefix-sum of the 3 dst-degree arrays
// ---------------------------------------------------------------------------
__global__ __launch_bounds__(1024)
void scan3(const int* c0, const int* c1, const int* c2,
           int* r0, int* r1, int* r2,
           int* u0, int* u1, int* u2)
{
    const int n = N_OBJ;
    const int* cnt = (blockIdx.x == 0) ? c0 : (blockIdx.x == 1 ? c1 : c2);
    int* rp  = (blockIdx.x == 0) ? r0 : (blockIdx.x == 1 ? r1 : r2);
    int* cur = (blockIdx.x == 0) ? u0 : (blockIdx.x == 1 ? u1 : u2);

    __shared__ int part[1024];
    int t  = threadIdx.x;
    int lo = t * 20;
    int hi = lo + 20 < n ? lo + 20 : n;

    int local = 0;
    for (int i = lo; i < hi; ++i) local += cnt[i];
    part[t] = local;
    __syncthreads();
    for (int off = 1; off < 1024; off <<= 1) {
        int v = (t >= off) ? part[t - off] : 0;
        __syncthreads();
        part[t] += v;
        __syncthreads();
    }
    int run = part[t] - local;
    for (int i = lo; i < hi; ++i) {
        rp[i]  = run;
        cur[i] = run;
        run += cnt[i];
    }
    if (t == 1023) rp[n] = part[1023];
}

// ---------------------------------------------------------------------------
// norm = 1/sqrt(max(deg,1)) for the 6 degree arrays
// ---------------------------------------------------------------------------
__global__ void norms6(const int* c0, const int* c1, const int* c2,
                       const int* c3, const int* c4, const int* c5,
                       float* n0, float* n1, float* n2,
                       float* n3, float* n4, float* n5,
                       int s0, int s1, int s2, int s3, int s4, int s5)
{
    const int* c; float* o; int n;
    switch (blockIdx.y) {
        case 0:  c = c0; o = n0; n = s0; break;
        case 1:  c = c1; o = n1; n = s1; break;
        case 2:  c = c2; o = n2; n = s2; break;
        case 3:  c = c3; o = n3; n = s3; break;
        case 4:  c = c4; o = n4; n = s4; break;
        default: c = c5; o = n5; n = s5; break;
    }
    int i = blockIdx.x * blockDim.x + threadIdx.x;
    if (i < n) {
        int d = c[i];
        if (d < 1) d = 1;
        o[i] = 1.0f / sqrtf((float)d);
    }
}

// ---------------------------------------------------------------------------
// Fill CSR column arrays using atomic cursors
// ---------------------------------------------------------------------------
__global__ void fill_edges(const int* __restrict__ src_oo, const int* __restrict__ dst_oo,
                           const int* __restrict__ src_ro, const int* __restrict__ dst_ro,
                           const int* __restrict__ src_ao, const int* __restrict__ dst_ao,
                           int* cur_oo, int* cur_ro, int* cur_ao,
                           int* col_oo, int* col_ro, int* col_ao)
{
    int e = blockIdx.x * blockDim.x + threadIdx.x;
    const int total = E_OO + E_RO + E_AO;
    if (e >= total) return;
    if (e < E_OO) {
        int pos = atomicAdd(&cur_oo[dst_oo[e]], 1);
        col_oo[pos] = src_oo[e];
    } else if (e < E_OO + E_RO) {
        int i = e - E_OO;
        int pos = atomicAdd(&cur_ro[dst_ro[i]], 1);
        col_ro[pos] = src_ro[i];
    } else {
        int i = e - E_OO - E_RO;
        int pos = atomicAdd(&cur_ao[dst_ao[i]], 1);
        col_ao[pos] = src_ao[i];
    }
}

// ---------------------------------------------------------------------------
// Pack weight: Wp is n-major [HDIM][3*Kp] bf16 bits, rows: [Wh | Wl | Wh]
// (A-side supplies Ah for terms 0,1 and Al for term 2.)
// ---------------------------------------------------------------------------
__global__ void pack_w(const float* __restrict__ W, int K, int Kp,
                       unsigned short* __restrict__ Wp)
{
    int Keff = 3 * Kp;
    int idx = blockIdx.x * 256 + threadIdx.x;
    if (idx >= HDIM * Keff) return;
    int n  = idx / Keff;
    int kp = idx - n * Keff;
    int term = (kp >= 2 * Kp) ? 2 : (kp >= Kp ? 1 : 0);
    int ks = kp - term * Kp;
    float v = (ks < K) ? W[(size_t)ks * HDIM + n] : 0.0f;
    unsigned short h = f2bf_rn(v);
    unsigned short out = (term == 1) ? f2bf_rn(v - bf2f(h)) : h;
    Wp[idx] = out;
}

// ---------------------------------------------------------------------------
// CSR aggregation with bf16 hi/lo split output.
// out rows are Fp wide (Kp-padded); pad cols written as 0.
// ---------------------------------------------------------------------------
__global__ __launch_bounds__(256)
void agg_csr_split(const float* __restrict__ feat, int F, int Fp,
                   const int* __restrict__ rp, const int* __restrict__ col,
                   const float* __restrict__ nsrc, const float* __restrict__ ndst,
                   float scale,
                   unsigned short* __restrict__ hi, unsigned short* __restrict__ lo)
{
    int d = blockIdx.x;
    int t = threadIdx.x;
    int a = rp[d], b = rp[d + 1];
    int f2 = 256 + t;
    bool has2  = (f2 < Fp);
    bool real2 = (f2 < F);
    float acc0 = 0.f, acc1 = 0.f;
    for (int j = a; j < b; ++j) {
        int s = col[j];
        float ns = nsrc[s] * scale;
        acc0 += feat[(size_t)s * F + t] * ns;
        if (real2) acc1 += feat[(size_t)s * F + f2] * ns;
    }
    float nd = ndst[d];
    acc0 *= nd;
    acc1 = real2 ? acc1 * nd : 0.f;

    size_t o0 = (size_t)d * Fp + t;
    unsigned short h0 = f2bf_rn(acc0);
    hi[o0] = h0;
    lo[o0] = f2bf_rn(acc0 - bf2f(h0));
    if (has2) {
        size_t o1 = (size_t)d * Fp + f2;
        unsigned short h1 = f2bf_rn(acc1);
        hi[o1] = h1;
        lo[o1] = f2bf_rn(acc1 - bf2f(h1));
    }
}

// ---------------------------------------------------------------------------
// bf16 MFMA GEMM: C[M x 512] = epi( (Ah+Al) @ (Wh+Wl) + bias ), split into
// K_eff = 3*Kp: [0,Kp)=Ah@Wh, [Kp,2Kp)=Ah@Wl, [2Kp,3Kp)=Al@Wh.
// Wp is n-major [512][3Kp]. Block 256 thr = 4 waves, tile 128x128, BK=32.
// Each wave: 64x64 via 4x4 frags of v_mfma_f32_16x16x32_bf16.
// EPI: 0 = C=relu(v), 1 = C+=relu(v), 2 = out[0..7 slices]=v, 3 = C=v
// ---------------------------------------------------------------------------
template<int EPI>
__global__ __launch_bounds__(256)
void gemm_mfma(const unsigned short* __restrict__ Ah,
               const unsigned short* __restrict__ Al,
               const unsigned short* __restrict__ Wp,
               const float* __restrict__ bias,
               float* __restrict__ C,
               int M, int Kp)
{
    const int LDT = 40;                     // LDS row stride (u16); 80 B
    __shared__ unsigned short As[128 * LDT];
    __shared__ unsigned short Bs[128 * LDT];

    int tid  = threadIdx.x;
    int lane = tid & 63;
    int wave = tid >> 6;
    int wm = (wave & 1) * 64;
    int wn = (wave >> 1) * 64;
    int m0 = blockIdx.x * 128;
    int n0 = blockIdx.y * 128;
    int Keff = 3 * Kp;
    int rw = lane & 15;                     // fragment row index
    int q  = lane >> 4;                     // k-group

    f32x4 acc[4][4];
#pragma unroll
    for (int i = 0; i < 4; ++i)
#pragma unroll
        for (int j = 0; j < 4; ++j) acc[i][j] = (f32x4)0.0f;

    for (int k0 = 0; k0 < Keff; k0 += 32) {
        int term = (k0 >= 2 * Kp) ? 2 : (k0 >= Kp ? 1 : 0);
        int kb = k0 - ((term == 2) ? 2 * Kp : (term == 1 ? Kp : 0));
        const unsigned short* Asrc = (term == 2) ? Al : Ah;
#pragma unroll
        for (int h = 0; h < 2; ++h) {        // stage A: 128 x 32
            int idx = tid + h * 256;
            int m = idx >> 2, kc = (idx & 3) * 8;
            int gm = m0 + m;
            uint4 v = make_uint4(0u, 0u, 0u, 0u);
            if (gm < M) v = *(const uint4*)(Asrc + (size_t)gm * Kp + kb + kc);
            *(uint4*)&As[m * LDT + kc] = v;
        }
#pragma unroll
        for (int h = 0; h < 2; ++h) {        // stage B: 128 n-rows x 32 k
            int idx = tid + h * 256;
            int nn = idx >> 2, kc = (idx & 3) * 8;
            uint4 v = *(const uint4*)(Wp + (size_t)(n0 + nn) * Keff + k0 + kc);
            *(uint4*)&Bs[nn * LDT + kc] = v;
        }
        __syncthreads();

        bf16x8 af[4], bfr[4];
#pragma unroll
        for (int i = 0; i < 4; ++i) {
            af[i]  = __builtin_bit_cast(bf16x8, *(const uint4*)&As[(wm + i * 16 + rw) * LDT + q * 8]);
            bfr[i] = __builtin_bit_cast(bf16x8, *(const uint4*)&Bs[(wn + i * 16 + rw) * LDT + q * 8]);
        }
#pragma unroll
        for (int i = 0; i < 4; ++i)
#pragma unroll
            for (int j = 0; j < 4; ++j)
                acc[i][j] = __builtin_amdgcn_mfma_f32_16x16x32_bf16(af[i], bfr[j], acc[i][j], 0, 0, 0);
        __syncthreads();
    }

    // epilogue: D row = q*4 + r, col = rw (within each 16x16 frag)
    const size_t slice = (size_t)N_OBJ * HDIM;
#pragma unroll
    for (int j = 0; j < 4; ++j) {
        int n = n0 + wn + j * 16 + rw;
        float bv = bias[n];
#pragma unroll
        for (int i = 0; i < 4; ++i) {
#pragma unroll
            for (int r = 0; r < 4; ++r) {
                int m = m0 + wm + i * 16 + q * 4 + r;
                if (m < M) {
                    float v = acc[i][j][r] + bv;
                    size_t o = (size_t)m * HDIM + n;
                    if (EPI == 0)      C[o] = fmaxf(v, 0.f);
                    else if (EPI == 1) C[o] += fmaxf(v, 0.f);
                    else if (EPI == 2) {
#pragma unroll
                        for (int c = 0; c < BATCH; ++c) C[c * slice + o] = v;
                    } else             C[o] = v;
                }
            }
        }
    }
}

// ---------------------------------------------------------------------------
// Broadcast slice 0 of d_out into slices 1..7 (fallback path only)
// ---------------------------------------------------------------------------
__global__ void bcast8(const float4* __restrict__ src, float4* __restrict__ dst)
{
    const long long slice4 = (long long)N_OBJ * HDIM / 4;
    long long i = (long long)blockIdx.x * blockDim.x + threadIdx.x;
    float4 v = src[i];
#pragma unroll
    for (int c = 1; c < BATCH; ++c)
        dst[c * slice4 + i] = v;
}

// ---------------------------------------------------------------------------
extern "C" void kernel_launch(void* const* d_in, const int* in_sizes, int n_in,
                              void* d_out, int out_size, void* d_ws, size_t ws_size,
                              hipStream_t stream)
{
    const float* feat_object = (const float*)d_in[1];
    const float* feat_room   = (const float*)d_in[2];
    const float* feat_attr   = (const float*)d_in[3];
    const float* W1i = (const float*)d_in[4];
    const float* b1i = (const float*)d_in[5];
    const float* W1b = (const float*)d_in[6];
    const float* b1b = (const float*)d_in[7];
    const float* W2  = (const float*)d_in[8];
    const float* b2  = (const float*)d_in[9];
    const int* src_oo = (const int*)d_in[10];
    const int* dst_oo = (const int*)d_in[11];
    const int* src_ro = (const int*)d_in[12];
    const int* dst_ro = (const int*)d_in[13];
    const int* src_ao = (const int*)d_in[14];
    const int* dst_ao = (const int*)d_in[15];
    float* out = (float*)d_out;

    const size_t slice = (size_t)N_OBJ * HDIM;
    const int KP1 = 320;                 // 300 padded to 32
    const int KP2 = 512;

    // ---- scratch layout (~117 MB). Prefer d_ws (evidence: ws_size ~1.31 GB);
    // fall back to d_out slices 1..7 (286 MB, dead until the end) otherwise.
    const size_t NEED = 130u * 1024u * 1024u;
    bool use_ws = (ws_size >= NEED);
    char* base = use_ws ? (char*)d_ws : (char*)(out + slice);
    size_t off = 0;
    auto alloc = [&](size_t bytes) -> void* {
        void* p = base + off;
        off += (bytes + 255) & ~(size_t)255;
        return p;
    };

    float* n_src_oo = (float*)alloc(N_OBJ  * 4);
    float* n_src_ro = (float*)alloc(N_ROOM * 4);
    float* n_src_ao = (float*)alloc(N_ATTR * 4);
    float* n_dst_oo = (float*)alloc(N_OBJ * 4);
    float* n_dst_ro = (float*)alloc(N_OBJ * 4);
    float* n_dst_ao = (float*)alloc(N_OBJ * 4);

    const int CNT_TOTAL = N_OBJ + 512 + 2048 + 3 * N_OBJ;
    int* cnt_blk    = (int*)alloc((size_t)CNT_TOTAL * 4);
    int* cnt_src_oo = cnt_blk;
    int* cnt_src_ro = cnt_src_oo + N_OBJ;
    int* cnt_src_ao = cnt_src_ro + 512;
    int* cnt_dst_oo = cnt_src_ao + 2048;
    int* cnt_dst_ro = cnt_dst_oo + N_OBJ;
    int* cnt_dst_ao = cnt_dst_ro + N_OBJ;

    int* rp_oo  = (int*)alloc((N_OBJ + 1) * 4);
    int* rp_ro  = (int*)alloc((N_OBJ + 1) * 4);
    int* rp_ao  = (int*)alloc((N_OBJ + 1) * 4);
    int* cur_oo = (int*)alloc(N_OBJ * 4);
    int* cur_ro = (int*)alloc(N_OBJ * 4);
    int* cur_ao = (int*)alloc(N_OBJ * 4);
    int* col_oo = (int*)alloc((size_t)E_OO * 4);
    int* col_ro = (int*)alloc((size_t)E_RO * 4);
    int* col_ao = (int*)alloc((size_t)E_AO * 4);

    unsigned short* Ah1 = (unsigned short*)alloc((size_t)N_OBJ * KP1 * 2);
    unsigned short* Al1 = (unsigned short*)alloc((size_t)N_OBJ * KP1 * 2);
    unsigned short* Ah2 = (unsigned short*)alloc((size_t)N_OBJ * KP2 * 2);
    unsigned short* Al2 = (unsigned short*)alloc((size_t)N_OBJ * KP2 * 2);
    unsigned short* Wp1i = (unsigned short*)alloc((size_t)HDIM * 3 * KP1 * 2);
    unsigned short* Wp1b = (unsigned short*)alloc((size_t)HDIM * 3 * KP1 * 2);
    unsigned short* Wp2  = (unsigned short*)alloc((size_t)HDIM * 3 * KP2 * 2);
    float* h_sum = (float*)alloc(slice * 4);

    // ---- CSR build ----
    hipMemsetAsync(cnt_blk, 0, (size_t)CNT_TOTAL * 4, stream);
    const int TOTAL_E = E_OO + E_RO + E_AO;
    int egrid = (TOTAL_E + 255) / 256;
    count_edges<<<egrid, 256, 0, stream>>>(src_oo, dst_oo, src_ro, dst_ro, src_ao, dst_ao,
                                           cnt_src_oo, cnt_src_ro, cnt_src_ao,
                                           cnt_dst_oo, cnt_dst_ro, cnt_dst_ao);
    scan3<<<3, 1024, 0, stream>>>(cnt_dst_oo, cnt_dst_ro, cnt_dst_ao,
                                  rp_oo, rp_ro, rp_ao, cur_oo, cur_ro, cur_ao);
    norms6<<<dim3((N_OBJ + 255) / 256, 6), 256, 0, stream>>>(
        cnt_src_oo, cnt_src_ro, cnt_src_ao, cnt_dst_oo, cnt_dst_ro, cnt_dst_ao,
        n_src_oo, n_src_ro, n_src_ao, n_dst_oo, n_dst_ro, n_dst_ao,
        N_OBJ, N_ROOM, N_ATTR, N_OBJ, N_OBJ, N_OBJ);
    fill_edges<<<egrid, 256, 0, stream>>>(src_oo, dst_oo, src_ro, dst_ro, src_ao, dst_ao,
                                          cur_oo, cur_ro, cur_ao, col_oo, col_ro, col_ao);

    // ---- weight packing (hi/lo split, n-major) ----
    {
        int e1 = HDIM * 3 * KP1, e2 = HDIM * 3 * KP2;
        pack_w<<<(e1 + 255) / 256, 256, 0, stream>>>(W1i, IN_F, KP1, Wp1i);
        pack_w<<<(e1 + 255) / 256, 256, 0, stream>>>(W1b, IN_F, KP1, Wp1b);
        pack_w<<<(e2 + 255) / 256, 256, 0, stream>>>(W2, HDIM, KP2, Wp2);
    }

    dim3 ggrid((N_OBJ + 127) / 128, HDIM / 128);

    // ---- conv1 (three relations, relu-then-sum into h_sum) ----
    agg_csr_split<<<N_OBJ, 256, 0, stream>>>(feat_object, IN_F, KP1, rp_oo, col_oo,
                                             n_src_oo, n_dst_oo, 1.0f, Ah1, Al1);
    gemm_mfma<0><<<ggrid, 256, 0, stream>>>(Ah1, Al1, Wp1i, b1i, h_sum, N_OBJ, KP1);

    agg_csr_split<<<N_OBJ, 256, 0, stream>>>(feat_room, IN_F, KP1, rp_ro, col_ro,
                                             n_src_ro, n_dst_ro, 1.0f, Ah1, Al1);
    gemm_mfma<1><<<ggrid, 256, 0, stream>>>(Ah1, Al1, Wp1i, b1i, h_sum, N_OBJ, KP1);

    agg_csr_split<<<N_OBJ, 256, 0, stream>>>(feat_attr, IN_F, KP1, rp_ao, col_ao,
                                             n_src_ao, n_dst_ao, 1.0f, Ah1, Al1);
    gemm_mfma<1><<<ggrid, 256, 0, stream>>>(Ah1, Al1, Wp1b, b1b, h_sum, N_OBJ, KP1);

    // ---- conv2 (oo graph on h_obj = h_sum/3; scale folded into agg) ----
    agg_csr_split<<<N_OBJ, 256, 0, stream>>>(h_sum, HDIM, KP2, rp_oo, col_oo,
                                             n_src_oo, n_dst_oo, 1.0f / 3.0f, Ah2, Al2);
    if (use_ws) {
        gemm_mfma<2><<<ggrid, 256, 0, stream>>>(Ah2, Al2, Wp2, b2, out, N_OBJ, KP2);
    } else {
        gemm_mfma<3><<<ggrid, 256, 0, stream>>>(Ah2, Al2, Wp2, b2, out, N_OBJ, KP2);
        const long long slice4 = (long long)slice / 4;
        bcast8<<<(unsigned)(slice4 / 256), 256, 0, stream>>>((const float4*)out, (float4*)out);
    }
}